// Round 1
// 1027.131 us; speedup vs baseline: 1.3649x; 1.3649x over previous
//
#include <hip/hip_runtime.h>

#define N_ENTITIES 300000
#define N_ITEMS    150000
#define N_USERS    150000
#define N_EDGES    2000000
#define N_INTER    2000000
#define D          64
#define N_TOT      (N_ENTITIES + N_ITEMS + N_USERS)   // 600000

// ===========================================================================
// Pass 1: histogram + rank. The atomic's return value IS the within-bucket
// rank, so the later payload scatter needs no atomics at all.
// ===========================================================================
__global__ void hist_rank_kernel(const int* __restrict__ head,
                                 const int* __restrict__ mat_col,
                                 const int* __restrict__ mat_row,
                                 int* __restrict__ cnt,
                                 int* __restrict__ r_ent,
                                 int* __restrict__ r_item,
                                 int* __restrict__ r_user) {
    int e = blockIdx.x * 256 + threadIdx.x;
    if (e >= N_EDGES) return;
    int h = head[e], c = mat_col[e], r = mat_row[e];
    int a0 = atomicAdd(&cnt[h], 1);
    int a1 = atomicAdd(&cnt[N_ENTITIES + c], 1);
    int a2 = atomicAdd(&cnt[N_ENTITIES + N_ITEMS + r], 1);
    r_ent[e]  = a0;
    r_item[e] = a1;
    r_user[e] = a2;
}

// One-time 2x 64x64 transpose of the gate matrices into workspace so the
// agg_item LDS staging is coalesced-read + conflict-free-write.
__global__ void transpose_gates_kernel(const float* __restrict__ g1,
                                       const float* __restrict__ g2,
                                       float* __restrict__ g1t,
                                       float* __restrict__ g2t) {
    int i = blockIdx.x * 256 + threadIdx.x;
    if (i >= 64 * 64) return;
    int o = i >> 6, k = i & 63;
    g1t[k * 64 + o] = g1[i];
    g2t[k * 64 + o] = g2[i];
}

// ===========================================================================
// One scan over the whole 600K concatenated count array.
// ===========================================================================
__global__ __launch_bounds__(256) void scan_partial(const int* __restrict__ in,
                                                    int* __restrict__ incl,
                                                    int* __restrict__ bsums,
                                                    int n) {
    __shared__ int lds[256];
    int t = threadIdx.x;
    int base = blockIdx.x * 1024 + t * 4;
    int v0 = (base + 0 < n) ? in[base + 0] : 0;
    int v1 = (base + 1 < n) ? in[base + 1] : 0;
    int v2 = (base + 2 < n) ? in[base + 2] : 0;
    int v3 = (base + 3 < n) ? in[base + 3] : 0;
    int s = v0 + v1 + v2 + v3;
    lds[t] = s;
    __syncthreads();
    for (int off = 1; off < 256; off <<= 1) {
        int x = (t >= off) ? lds[t - off] : 0;
        __syncthreads();
        lds[t] += x;
        __syncthreads();
    }
    int excl = lds[t] - s;
    if (base + 0 < n) incl[base + 0] = excl + v0;
    if (base + 1 < n) incl[base + 1] = excl + v0 + v1;
    if (base + 2 < n) incl[base + 2] = excl + v0 + v1 + v2;
    if (base + 3 < n) incl[base + 3] = excl + s;
    if (t == 255) bsums[blockIdx.x] = lds[255];
}

__global__ __launch_bounds__(1024) void scan_bsums(int* __restrict__ bsums, int nb) {
    __shared__ int lds[1024];
    int t = threadIdx.x;
    lds[t] = (t < nb) ? bsums[t] : 0;
    __syncthreads();
    for (int off = 1; off < 1024; off <<= 1) {
        int x = (t >= off) ? lds[t - off] : 0;
        __syncthreads();
        lds[t] += x;
        __syncthreads();
    }
    if (t < nb) bsums[t] = lds[t];
}

__global__ void scan_finalize(const int* __restrict__ incl,
                              const int* __restrict__ bsums,
                              int* __restrict__ off_ent,
                              int* __restrict__ off_item,
                              int* __restrict__ off_user) {
    int i = blockIdx.x * 256 + threadIdx.x;
    if (i >= N_TOT) return;
    int b = i >> 10;
    int g = incl[i] + ((b > 0) ? bsums[b - 1] : 0);
    if (i < N_ENTITIES) {
        off_ent[i + 1] = g;
        if (i == 0) { off_ent[0] = 0; }
    } else if (i < N_ENTITIES + N_ITEMS) {
        off_item[i - N_ENTITIES + 1] = g - N_EDGES;
        if (i == N_ENTITIES) { off_item[0] = 0; }
    } else {
        off_user[i - N_ENTITIES - N_ITEMS + 1] = g - 2 * N_EDGES;
        if (i == N_ENTITIES + N_ITEMS) { off_user[0] = 0; }
    }
}

// ===========================================================================
// Pass 2: atomic-free payload scatter. pos = off[key] + rank.
// ===========================================================================
__global__ void scatter_all_kernel(const int* __restrict__ head,
                                   const int* __restrict__ tail,
                                   const int* __restrict__ type,
                                   const int* __restrict__ mat_row,
                                   const int* __restrict__ mat_col,
                                   const int* __restrict__ r_ent,
                                   const int* __restrict__ r_item,
                                   const int* __restrict__ r_user,
                                   const int* __restrict__ off_ent,
                                   const int* __restrict__ off_item,
                                   const int* __restrict__ off_user,
                                   int* __restrict__ tt_sorted,
                                   int* __restrict__ row_sorted,
                                   int* __restrict__ col_sorted) {
    int e = blockIdx.x * 256 + threadIdx.x;
    if (e >= N_EDGES) return;
    int h = head[e], t = tail[e], ty = type[e];
    int r = mat_row[e], c = mat_col[e];
    tt_sorted[off_ent[h] + r_ent[e]]   = t | (ty << 19);
    row_sorted[off_item[c] + r_item[e]] = r;
    col_sorted[off_user[r] + r_user[e]] = c;
}

// ===========================================================================
// Gather aggregations — one wave per destination row; 4 lane-groups of 16
// each handle one gathered row per step with float4 (16B/lane) loads; row
// indices come from a 16B broadcast load (no ds_bpermute); cross-group
// reduce via 2x shfl_xor at the end.
// ===========================================================================
__global__ __launch_bounds__(256, 8) void agg_ent_kernel(
        const float* __restrict__ entity_emb, const float* __restrict__ weight,
        const int* __restrict__ off, const int* __restrict__ tt_sorted,
        float* __restrict__ out_item_kg, float* __restrict__ out_final) {
    int wave = threadIdx.x >> 6, lane = threadIdx.x & 63;
    int g = lane >> 4, q = lane & 15;
    int ent = blockIdx.x * 4 + wave;
    if (ent >= N_ENTITIES) return;
    int s = off[ent], e = off[ent + 1];
    int cnt = e - s;
    const float4* __restrict__ emb4 = (const float4*)entity_emb;
    const float4* __restrict__ wt4  = (const float4*)weight;
    float ax = 0.f, ay = 0.f, az = 0.f, aw = 0.f;
    for (int idx = s + g; idx < e; idx += 8) {
        int v0 = tt_sorted[idx];
        int i2 = idx + 4;
        bool p2 = (i2 < e);
        int v1 = p2 ? tt_sorted[i2] : 0;
        {
            int t = v0 & 0x7FFFF, w = v0 >> 19;
            float4 a = emb4[t * 16 + q];
            float4 b = wt4[w * 16 + q];
            ax += a.x * b.x; ay += a.y * b.y; az += a.z * b.z; aw += a.w * b.w;
        }
        if (p2) {
            int t = v1 & 0x7FFFF, w = v1 >> 19;
            float4 a = emb4[t * 16 + q];
            float4 b = wt4[w * 16 + q];
            ax += a.x * b.x; ay += a.y * b.y; az += a.z * b.z; aw += a.w * b.w;
        }
    }
    ax += __shfl_xor(ax, 16); ax += __shfl_xor(ax, 32);
    ay += __shfl_xor(ay, 16); ay += __shfl_xor(ay, 32);
    az += __shfl_xor(az, 16); az += __shfl_xor(az, 32);
    aw += __shfl_xor(aw, 16); aw += __shfl_xor(aw, 32);
    if (g == 0) {
        float inv = 1.0f / (float)(cnt > 1 ? cnt : 1);
        float4 r; r.x = ax * inv; r.y = ay * inv; r.z = az * inv; r.w = aw * inv;
        if (ent < N_ITEMS) ((float4*)out_item_kg)[ent * 16 + q] = r;
        else               ((float4*)out_final)[ent * 16 + q]   = r;
    }
}

// item_int mean + gate + fusion. Gate matrices live TRANSPOSED in LDS so
// each 16-lane group reads a contiguous 256B row slice (conflict-free b128);
// the k-range is split 16-per-group, reduced with shfl_xor.
// 512 threads = 8 items/block; 150000 = 8*18750 exactly (no early-exit, safe barrier).
__global__ __launch_bounds__(512, 6) void agg_item_fuse_kernel(
        const float* __restrict__ user_emb,
        const int* __restrict__ off, const int* __restrict__ row_sorted,
        const float* __restrict__ item_kg,
        const float* __restrict__ g1t, const float* __restrict__ g2t,
        float* __restrict__ out_item_int, float* __restrict__ out_final) {
    __shared__ float s_g1t[4096];
    __shared__ float s_g2t[4096];
    __shared__ float s_ii[8 * 64];

    {   // stage pre-transposed gates: coalesced global read, linear LDS write
        const float4* a = (const float4*)g1t;
        const float4* b = (const float4*)g2t;
        float4* sa = (float4*)s_g1t;
        float4* sb = (float4*)s_g2t;
        #pragma unroll
        for (int i = threadIdx.x; i < 1024; i += 512) { sa[i] = a[i]; sb[i] = b[i]; }
    }

    int wave = threadIdx.x >> 6, lane = threadIdx.x & 63;
    int g = lane >> 4, q = lane & 15;
    int item = blockIdx.x * 8 + wave;
    int s = off[item], e = off[item + 1];
    int cnt = e - s;
    const float4* __restrict__ ue4 = (const float4*)user_emb;
    float ax = 0.f, ay = 0.f, az = 0.f, aw = 0.f;
    for (int idx = s + g; idx < e; idx += 8) {
        int r0 = row_sorted[idx];
        int i2 = idx + 4;
        bool p2 = (i2 < e);
        int r1 = p2 ? row_sorted[i2] : 0;
        {
            float4 v = ue4[r0 * 16 + q];
            ax += v.x; ay += v.y; az += v.z; aw += v.w;
        }
        if (p2) {
            float4 v = ue4[r1 * 16 + q];
            ax += v.x; ay += v.y; az += v.z; aw += v.w;
        }
    }
    ax += __shfl_xor(ax, 16); ax += __shfl_xor(ax, 32);
    ay += __shfl_xor(ay, 16); ay += __shfl_xor(ay, 32);
    az += __shfl_xor(az, 16); az += __shfl_xor(az, 32);
    aw += __shfl_xor(aw, 16); aw += __shfl_xor(aw, 32);
    float inv = 1.0f / (float)(cnt > 1 ? cnt : 1);
    ax *= inv; ay *= inv; az *= inv; aw *= inv;       // ii, dims 4q..4q+3 (all lanes)
    if (g == 0) {
        float4 t; t.x = ax; t.y = ay; t.z = az; t.w = aw;
        *(float4*)&s_ii[wave * 64 + 4 * q] = t;
    }
    __syncthreads();   // gates staged + this wave's ii visible

    // gate: gacc[o] = sum_k kg[k]*g1[o,k] + ii[k]*g2[o,k]; group g covers k in [16g,16g+16)
    const float* __restrict__ kgrow = item_kg + (long long)item * 64;
    float gx = 0.f, gy = 0.f, gz = 0.f, gw = 0.f;
    #pragma unroll 4
    for (int i = 0; i < 16; ++i) {
        int k = 16 * g + i;
        float kk = kgrow[k];                 // 16B broadcast, L1-hot
        float ik = s_ii[wave * 64 + k];      // LDS broadcast within group
        float4 w1 = *(const float4*)&s_g1t[k * 64 + 4 * q];
        float4 w2 = *(const float4*)&s_g2t[k * 64 + 4 * q];
        gx += kk * w1.x + ik * w2.x;
        gy += kk * w1.y + ik * w2.y;
        gz += kk * w1.z + ik * w2.z;
        gw += kk * w1.w + ik * w2.w;
    }
    gx += __shfl_xor(gx, 16); gx += __shfl_xor(gx, 32);
    gy += __shfl_xor(gy, 16); gy += __shfl_xor(gy, 32);
    gz += __shfl_xor(gz, 16); gz += __shfl_xor(gz, 32);
    gw += __shfl_xor(gw, 16); gw += __shfl_xor(gw, 32);

    if (g == 0) {
        float4 kg4 = *(const float4*)&kgrow[4 * q];
        float4 ii4; ii4.x = ax; ii4.y = ay; ii4.z = az; ii4.w = aw;
        float4 o;
        float s0 = 1.0f / (1.0f + __expf(-gx)); o.x = s0 * kg4.x + (1.0f - s0) * ii4.x;
        float s1 = 1.0f / (1.0f + __expf(-gy)); o.y = s1 * kg4.y + (1.0f - s1) * ii4.y;
        float s2 = 1.0f / (1.0f + __expf(-gz)); o.z = s2 * kg4.z + (1.0f - s2) * ii4.z;
        float s3 = 1.0f / (1.0f + __expf(-gw)); o.w = s3 * kg4.w + (1.0f - s3) * ii4.w;
        ((float4*)out_item_int)[item * 16 + q] = ii4;
        ((float4*)out_final)[item * 16 + q]    = o;
    }
}

__global__ __launch_bounds__(256, 8) void agg_user_kernel(
        const float* __restrict__ fusion,   // = out_final[:N_ITEMS]
        const int* __restrict__ off, const int* __restrict__ col_sorted,
        float* __restrict__ out_user) {
    int wave = threadIdx.x >> 6, lane = threadIdx.x & 63;
    int g = lane >> 4, q = lane & 15;
    int user = blockIdx.x * 4 + wave;
    if (user >= N_USERS) return;
    int s = off[user], e = off[user + 1];
    const float4* __restrict__ f4 = (const float4*)fusion;
    float ax = 0.f, ay = 0.f, az = 0.f, aw = 0.f;
    for (int idx = s + g; idx < e; idx += 8) {
        int c0 = col_sorted[idx];
        int i2 = idx + 4;
        bool p2 = (i2 < e);
        int c1 = p2 ? col_sorted[i2] : 0;
        {
            float4 v = f4[c0 * 16 + q];
            ax += v.x; ay += v.y; az += v.z; aw += v.w;
        }
        if (p2) {
            float4 v = f4[c1 * 16 + q];
            ax += v.x; ay += v.y; az += v.z; aw += v.w;
        }
    }
    ax += __shfl_xor(ax, 16); ax += __shfl_xor(ax, 32);
    ay += __shfl_xor(ay, 16); ay += __shfl_xor(ay, 32);
    az += __shfl_xor(az, 16); az += __shfl_xor(az, 32);
    aw += __shfl_xor(aw, 16); aw += __shfl_xor(aw, 32);
    if (g == 0) {
        float4 r; r.x = ax; r.y = ay; r.z = az; r.w = aw;
        ((float4*)out_user)[user * 16 + q] = r;     // segment_sum (no mean)
    }
}

// ===========================================================================

extern "C" void kernel_launch(void* const* d_in, const int* in_sizes, int n_in,
                              void* d_out, int out_size, void* d_ws, size_t ws_size,
                              hipStream_t stream) {
    const float* entity_emb = (const float*)d_in[0];
    const float* user_emb   = (const float*)d_in[1];
    const int*   edge_index = (const int*)d_in[2];   // (2, N_EDGES)
    const int*   edge_type  = (const int*)d_in[3];
    const int*   mat_row    = (const int*)d_in[4];
    const int*   mat_col    = (const int*)d_in[5];
    const float* weight     = (const float*)d_in[6];
    const float* g1         = (const float*)d_in[7];
    const float* g2         = (const float*)d_in[8];

    const int* edge_head = edge_index;
    const int* edge_tail = edge_index + N_EDGES;

    float* out = (float*)d_out;
    float* out_final    = out;                                   // [300000,64]
    float* out_user     = out + (long long)N_ENTITIES * D;       // [150000,64]
    float* out_item_kg  = out_user + (long long)N_USERS * D;     // [150000,64]
    float* out_item_int = out_item_kg + (long long)N_ITEMS * D;  // [150000,64]

    // ---- workspace layout (g1t/g2t first: they need 16B alignment) ----
    int* w = (int*)d_ws;
    float* g1t_glob = (float*)w;  w += 64 * 64;
    float* g2t_glob = (float*)w;  w += 64 * 64;
    int* cnt       = w;  w += N_TOT;            // concat [ent|item|user], zeroed
    int* off_ent   = w;  w += N_ENTITIES + 1;
    int* off_item  = w;  w += N_ITEMS + 1;
    int* off_user  = w;  w += N_USERS + 1;
    int* incl_tmp  = w;  w += N_TOT;
    int* bsums     = w;  w += 1024;
    int* r_ent     = w;  w += N_EDGES;
    int* r_item    = w;  w += N_INTER;
    int* r_user    = w;  w += N_INTER;
    int* tt_sorted = w;  w += N_EDGES;
    int* row_sorted= w;  w += N_INTER;
    int* col_sorted= w;  w += N_INTER;

    hipMemsetAsync(cnt, 0, (size_t)N_TOT * sizeof(int), stream);

    const int EB = (N_EDGES + 255) / 256;

    // 0) one-time gate transpose (tiny; deep ahead of agg_item in the stream)
    transpose_gates_kernel<<<16, 256, 0, stream>>>(g1, g2, g1t_glob, g2t_glob);

    // 1) histogram + within-bucket ranks (the only atomics in the pipeline)
    hist_rank_kernel<<<EB, 256, 0, stream>>>(edge_head, mat_col, mat_row,
                                             cnt, r_ent, r_item, r_user);

    // 2) one concatenated prefix sum -> three offset arrays
    {
        int nb = (N_TOT + 1023) / 1024;
        scan_partial<<<nb, 256, 0, stream>>>(cnt, incl_tmp, bsums, N_TOT);
        scan_bsums<<<1, 1024, 0, stream>>>(bsums, nb);
        scan_finalize<<<(N_TOT + 255) / 256, 256, 0, stream>>>(
            incl_tmp, bsums, off_ent, off_item, off_user);
    }

    // 3) atomic-free payload scatter
    scatter_all_kernel<<<EB, 256, 0, stream>>>(
        edge_head, edge_tail, edge_type, mat_row, mat_col,
        r_ent, r_item, r_user, off_ent, off_item, off_user,
        tt_sorted, row_sorted, col_sorted);

    // 4) gather aggregations
    agg_ent_kernel<<<N_ENTITIES / 4, 256, 0, stream>>>(
        entity_emb, weight, off_ent, tt_sorted, out_item_kg, out_final);
    agg_item_fuse_kernel<<<N_ITEMS / 8, 512, 0, stream>>>(
        user_emb, off_item, row_sorted, out_item_kg, g1t_glob, g2t_glob,
        out_item_int, out_final);
    agg_user_kernel<<<N_USERS / 4, 256, 0, stream>>>(
        out_final, off_user, col_sorted, out_user);
}